// Round 6
// baseline (263.961 us; speedup 1.0000x reference)
//
#include <hip/hip_runtime.h>

// LSTM: B=32768, T=28, D=28, H=8, gates=32, classes=10.
//
// Two-phase structure. Rounds 2-5 proved the AMDGPU backend will not keep
// loop-invariant global loads (W) in VGPRs across a SERIAL loop -- it
// remats/sinks them into the loop, putting reload latency on the recurrence
// chain. Fix: make the heavy FMA work parallel so reloads don't matter.
//   Phase 1 (parallel over t): lane g computes xhat[e][t][g] =
//     b_g + x_t . W[0:28,g] for all t into LDS. Iterations independent ->
//     load latency pipelines away even if W reloads per iteration.
//   Phase 2 (serial over t): gate_g = xhat[t][g] + h . W[28:36,g] -- only
//     8 FMA on the chain; shfl_xor gathers (i,j,f,o); h exchanged via a
//     wave-synchronous LDS slot (structure validated in round 5).
// 32 lanes per element; no block-level barriers (groups self-contained).
// 4096 blocks x 256 threads.

#define TSTEPS 28
#define DIN    28
#define NH     8
#define NG     32
#define NC     10

__device__ __forceinline__ float fast_exp2(float x) {
    return __builtin_amdgcn_exp2f(x);
}
__device__ __forceinline__ float fast_rcp(float x) {
    return __builtin_amdgcn_rcpf(x);
}
__device__ __forceinline__ float fast_sigmoid(float z) {
    return fast_rcp(1.0f + fast_exp2(-1.4426950408889634f * z));
}
__device__ __forceinline__ float fast_tanh(float z) {
    return 1.0f - 2.0f * fast_rcp(1.0f + fast_exp2(2.8853900817779268f * z));
}

__global__ __launch_bounds__(256, 4) void lstm_kernel(
    const float* __restrict__ x,      // [B, T, D]
    const float* __restrict__ W,      // [36, 32]  col order i,j,f,o
    const float* __restrict__ bias,   // [32]
    const float* __restrict__ Wout,   // [8, 10]
    const float* __restrict__ bout,   // [10]
    float* __restrict__ out)          // [B, 10]
{
    const int tid  = blockIdx.x * 256 + threadIdx.x;
    const int e    = tid >> 5;             // batch element
    const int g    = tid & 31;             // gate column owned by this lane
    const int widx = threadIdx.x >> 5;     // element slot within block (0..7)

    __shared__ float xhat[8][TSTEPS][NG];          // 28672 B
    __shared__ __align__(16) float hsm[8][NH];     // h exchange slots

    const float* xb = x + (size_t)e * (TSTEPS * DIN);

    // ---------------- Phase 1: xhat[t][g] = b_g + x_t . W[0:28, g] --------
    float Wc[DIN];
#pragma unroll
    for (int k = 0; k < DIN; ++k)
        Wc[k] = W[k * NG + g];
    const float bg = bias[g];

#pragma unroll 2
    for (int t = 0; t < TSTEPS; ++t) {
        const float4* xv = (const float4*)(xb + t * DIN);
        float4 q0 = xv[0], q1 = xv[1], q2 = xv[2], q3 = xv[3],
               q4 = xv[4], q5 = xv[5], q6 = xv[6];
        float acc = bg;
        acc = fmaf(q0.x, Wc[ 0], acc); acc = fmaf(q0.y, Wc[ 1], acc);
        acc = fmaf(q0.z, Wc[ 2], acc); acc = fmaf(q0.w, Wc[ 3], acc);
        acc = fmaf(q1.x, Wc[ 4], acc); acc = fmaf(q1.y, Wc[ 5], acc);
        acc = fmaf(q1.z, Wc[ 6], acc); acc = fmaf(q1.w, Wc[ 7], acc);
        acc = fmaf(q2.x, Wc[ 8], acc); acc = fmaf(q2.y, Wc[ 9], acc);
        acc = fmaf(q2.z, Wc[10], acc); acc = fmaf(q2.w, Wc[11], acc);
        acc = fmaf(q3.x, Wc[12], acc); acc = fmaf(q3.y, Wc[13], acc);
        acc = fmaf(q3.z, Wc[14], acc); acc = fmaf(q3.w, Wc[15], acc);
        acc = fmaf(q4.x, Wc[16], acc); acc = fmaf(q4.y, Wc[17], acc);
        acc = fmaf(q4.z, Wc[18], acc); acc = fmaf(q4.w, Wc[19], acc);
        acc = fmaf(q5.x, Wc[20], acc); acc = fmaf(q5.y, Wc[21], acc);
        acc = fmaf(q5.z, Wc[22], acc); acc = fmaf(q5.w, Wc[23], acc);
        acc = fmaf(q6.x, Wc[24], acc); acc = fmaf(q6.y, Wc[25], acc);
        acc = fmaf(q6.z, Wc[26], acc); acc = fmaf(q6.w, Wc[27], acc);
        xhat[widx][t][g] = acc;
    }

    // ---------------- Phase 2: the recurrence ------------------------------
    float Wh[NH];
#pragma unroll
    for (int k = 0; k < NH; ++k)
        Wh[k] = W[(DIN + k) * NG + g];

    float c = 0.0f;
    float hall[NH];
#pragma unroll
    for (int j = 0; j < NH; ++j) hall[j] = 0.0f;

    __builtin_amdgcn_wave_barrier();   // keep phase-1 LDS writes ordered

#pragma unroll
    for (int t = 0; t < TSTEPS; ++t) {
        // xhat read is independent of h -> scheduler can hoist it early
        float acc = xhat[widx][t][g];
#pragma unroll
        for (int k = 0; k < NH; ++k)
            acc = fmaf(hall[k], Wh[k], acc);

        // Gather (i,j,f,o) of unit u = g&7: lanes u,u+8,u+16,u+24 hold them.
        float v1 = __shfl_xor(acc, 8);    // lane u: j_u
        float v2 = __shfl_xor(acc, 16);   // lane u: f_u
        float v3 = __shfl_xor(v1, 16);    // lane u: o_u

        float ig = fast_sigmoid(acc);
        float jg = fast_tanh(v1);
        float fg = fast_sigmoid(v2 + 1.0f);
        float og = fast_sigmoid(v3);
        c = c * fg + ig * jg;
        float hu = fast_tanh(c) * og;

        // Wave-synchronous h exchange through LDS (validated in round 5)
        if (g < NH) hsm[widx][g] = hu;
        __builtin_amdgcn_wave_barrier();
        float4 h01 = *(const float4*)&hsm[widx][0];
        float4 h23 = *(const float4*)&hsm[widx][4];
        __builtin_amdgcn_wave_barrier();
        hall[0] = h01.x; hall[1] = h01.y; hall[2] = h01.z; hall[3] = h01.w;
        hall[4] = h23.x; hall[5] = h23.y; hall[6] = h23.z; hall[7] = h23.w;
    }

    // logits = h @ Wout + bout; lanes 0-9 of each 32-group write one column
    if (g < NC) {
        float acc = bout[g];
#pragma unroll
        for (int k = 0; k < NH; ++k)
            acc = fmaf(hall[k], Wout[k * NC + g], acc);
        out[(size_t)e * NC + g] = acc;
    }
}

extern "C" void kernel_launch(void* const* d_in, const int* in_sizes, int n_in,
                              void* d_out, int out_size, void* d_ws, size_t ws_size,
                              hipStream_t stream) {
    const float* x    = (const float*)d_in[0];
    const float* W    = (const float*)d_in[1];
    const float* b    = (const float*)d_in[2];
    const float* Wout = (const float*)d_in[3];
    const float* bout = (const float*)d_in[4];
    float* out = (float*)d_out;

    const int B = in_sizes[0] / (TSTEPS * DIN);  // 32768
    const int threads = B * NG;                  // 1048576
    const int block = 256;
    const int grid = threads / block;            // 4096
    lstm_kernel<<<grid, block, 0, stream>>>(x, W, b, Wout, bout, out);
}

// Round 7
// 183.149 us; speedup vs baseline: 1.4412x; 1.4412x over previous
//
#include <hip/hip_runtime.h>

// LSTM: B=32768, T=28, D=28, H=8, gates=32, classes=10.
//
// Rounds 2-6 lesson: any structure where lane-indexed W must be re-read in
// the loop is TA/VMEM-issue bound (~40% VALUBusy) because the backend always
// remats per-lane W loads. Fix: make all heavy-phase W indices WAVE-UNIFORM
// so they compile to s_load (scalar pipe / K$ -- no TA pressure, one load
// per wave, remat harmless).
//
// Phase 1 (parallel): lane = one (element,t) row; computes all 32 gate
//   pre-acts = 28 bursts of 32 INDEPENDENT fma chains, W via s_load.
//   224 of 256 lanes active (8 elements x 28 steps). -> xhat in LDS.
// Phase 2 (serial): R6's recurrence; 8 recurrent weights read from an LDS
//   copy (DS pipe, remat-proof); h exchanged via wave-synchronous LDS slot.
// 4096 blocks x 256 threads.

#define TSTEPS 28
#define DIN    28
#define NH     8
#define NG     32
#define NC     10
#define TPAD   29   // pad t-dim: 29 coprime 32 -> conflict-free xhat access

__device__ __forceinline__ float fast_exp2(float x) {
    return __builtin_amdgcn_exp2f(x);
}
__device__ __forceinline__ float fast_rcp(float x) {
    return __builtin_amdgcn_rcpf(x);
}
__device__ __forceinline__ float fast_sigmoid(float z) {
    return fast_rcp(1.0f + fast_exp2(-1.4426950408889634f * z));
}
__device__ __forceinline__ float fast_tanh(float z) {
    return 1.0f - 2.0f * fast_rcp(1.0f + fast_exp2(2.8853900817779268f * z));
}

__global__ __launch_bounds__(256, 4) void lstm_kernel(
    const float* __restrict__ x,      // [B, T, D]
    const float* __restrict__ W,      // [36, 32]  col order i,j,f,o
    const float* __restrict__ bias,   // [32]
    const float* __restrict__ Wout,   // [8, 10]
    const float* __restrict__ bout,   // [10]
    float* __restrict__ out)          // [B, 10]
{
    const int L    = threadIdx.x;
    const int eblk = blockIdx.x * 8;           // 8 elements per block

    __shared__ float xhat[8][NG][TPAD];        // 29696 B
    __shared__ float Whs[NH][NG];              // recurrent weights, 1 KB
    __shared__ __align__(16) float hsm[8][NH]; // h exchange slots

    // Stage recurrent weights: thread L copies W[896 + L] (coalesced).
    Whs[L >> 5][L & 31] = W[(DIN * NG) + L];

    // ---------------- Phase 1: xhat[le][g][t] = b_g + x_t . W[:,g] --------
    if (L < 224) {
        const int le = L / 28;                 // element slot 0..7
        const int t  = L - le * 28;            // timestep 0..27
        const float4* xv =
            (const float4*)(x + ((size_t)(eblk + le) * TSTEPS + t) * DIN);
        float4 q[7];
#pragma unroll
        for (int i = 0; i < 7; ++i) q[i] = xv[i];

        float acc[NG];
#pragma unroll
        for (int g = 0; g < NG; ++g) acc[g] = bias[g];  // uniform -> s_load

        // 28 k-bursts x 32 independent chains; W index is compile-time
        // uniform -> s_load (scalar pipe), FMA reads it as SGPR operand.
#pragma unroll
        for (int i = 0; i < 7; ++i) {
            const float x0 = q[i].x, x1 = q[i].y, x2 = q[i].z, x3 = q[i].w;
#pragma unroll
            for (int g = 0; g < NG; ++g) {
                float a = acc[g];
                a = fmaf(x0, W[(4*i+0)*NG + g], a);
                a = fmaf(x1, W[(4*i+1)*NG + g], a);
                a = fmaf(x2, W[(4*i+2)*NG + g], a);
                a = fmaf(x3, W[(4*i+3)*NG + g], a);
                acc[g] = a;
            }
        }
        // Transposed store: addr dword = le*928 + g*29 + t; conflict-free.
#pragma unroll
        for (int g = 0; g < NG; ++g) xhat[le][g][t] = acc[g];
    }

    __syncthreads();

    // ---------------- Phase 2: the recurrence ------------------------------
    const int grp = L >> 5;                    // element slot 0..7
    const int g   = L & 31;                    // gate column 0..31

    float c = 0.0f;
    float hall[NH];
#pragma unroll
    for (int j = 0; j < NH; ++j) hall[j] = 0.0f;

#pragma unroll
    for (int t = 0; t < TSTEPS; ++t) {
        // xhat & Whs reads are h-independent -> scheduler hoists them early.
        float acc = xhat[grp][g][t];
#pragma unroll
        for (int k = 0; k < NH; ++k)
            acc = fmaf(hall[k], Whs[k][g], acc);

        // Gather (i,j,f,o) of unit u = g&7: lanes u,u+8,u+16,u+24 hold them.
        float v1 = __shfl_xor(acc, 8);    // lane u: j_u
        float v2 = __shfl_xor(acc, 16);   // lane u: f_u
        float v3 = __shfl_xor(v1, 16);    // lane u: o_u

        float ig = fast_sigmoid(acc);
        float jg = fast_tanh(v1);
        float fg = fast_sigmoid(v2 + 1.0f);
        float og = fast_sigmoid(v3);
        c = c * fg + ig * jg;
        float hu = fast_tanh(c) * og;

        // Wave-synchronous h exchange (validated rounds 5-6).
        if (g < NH) hsm[grp][g] = hu;
        __builtin_amdgcn_wave_barrier();
        float4 h01 = *(const float4*)&hsm[grp][0];
        float4 h23 = *(const float4*)&hsm[grp][4];
        __builtin_amdgcn_wave_barrier();
        hall[0] = h01.x; hall[1] = h01.y; hall[2] = h01.z; hall[3] = h01.w;
        hall[4] = h23.x; hall[5] = h23.y; hall[6] = h23.z; hall[7] = h23.w;
    }

    // logits = h @ Wout + bout; lanes 0-9 of each group write one column
    if (g < NC) {
        float acc = bout[g];
#pragma unroll
        for (int k = 0; k < NH; ++k)
            acc = fmaf(hall[k], Wout[k * NC + g], acc);
        out[(size_t)(eblk + grp) * NC + g] = acc;
    }
}

extern "C" void kernel_launch(void* const* d_in, const int* in_sizes, int n_in,
                              void* d_out, int out_size, void* d_ws, size_t ws_size,
                              hipStream_t stream) {
    const float* x    = (const float*)d_in[0];
    const float* W    = (const float*)d_in[1];
    const float* b    = (const float*)d_in[2];
    const float* Wout = (const float*)d_in[3];
    const float* bout = (const float*)d_in[4];
    float* out = (float*)d_out;

    const int B = in_sizes[0] / (TSTEPS * DIN);  // 32768
    const int grid = B / 8;                      // 4096 blocks
    lstm_kernel<<<grid, 256, 0, stream>>>(x, W, b, Wout, bout, out);
}